// Round 1
// baseline (414.908 us; speedup 1.0000x reference)
//
#include <hip/hip_runtime.h>
#include <math.h>

#define NORM_C (-8.3255483f)   /* -log(32+4096) */

typedef __attribute__((ext_vector_type(8))) short bf16x8;
typedef __attribute__((ext_vector_type(4))) float f32x4;

union U8 { uint4 q; unsigned u[4]; bf16x8 v; };

__device__ inline unsigned short f2bf_rne(float f) {
    unsigned u = __float_as_uint(f);
    unsigned r = u + 0x7fffu + ((u >> 16) & 1u);
    return (unsigned short)(r >> 16);
}
// pack two floats -> (bf16(hi)<<16)|bf16(lo)
__device__ inline unsigned pack_bf2(float lo, float hi) {
    unsigned a = __float_as_uint(lo) + 0x8000u;
    unsigned b = __float_as_uint(hi) + 0x8000u;
    return __builtin_amdgcn_perm(b, a, 0x07060302u);
}

// ---------------------------------------------------------------------------
// K0: fused prep. blocks 0..767: conv_w fp32->bf16. blocks 768..799: normalize
// clusters v[32][256] -> bf16.
// ---------------------------------------------------------------------------
__global__ __launch_bounds__(64) void w_prep(const float* __restrict__ W,
                                             const float* __restrict__ v_in,
                                             unsigned short* __restrict__ Wb,
                                             unsigned short* __restrict__ wnb) {
    const int bx = blockIdx.x, tid = threadIdx.x;
    if (bx < 768) {
        int i = (bx * 64 + tid) * 4;
        float4 w = *(const float4*)(W + i);
        unsigned lo = (unsigned)f2bf_rne(w.x) | ((unsigned)f2bf_rne(w.y) << 16);
        unsigned hi = (unsigned)f2bf_rne(w.z) | ((unsigned)f2bf_rne(w.w) << 16);
        *(uint2*)(Wb + i) = make_uint2(lo, hi);
    } else {
        int row = bx - 768;
        float4 v = *(const float4*)(v_in + row * 256 + tid * 4);
        float s = v.x * v.x + v.y * v.y + v.z * v.z + v.w * v.w;
#pragma unroll
        for (int off = 32; off > 0; off >>= 1) s += __shfl_xor(s, off);
        float inv = 1.0f / fmaxf(sqrtf(s), 1e-12f);
        unsigned lo = (unsigned)f2bf_rne(v.x * inv) | ((unsigned)f2bf_rne(v.y * inv) << 16);
        unsigned hi = (unsigned)f2bf_rne(v.z * inv) | ((unsigned)f2bf_rne(v.w * inv) << 16);
        *(uint2*)(wnb + row * 256 + tid * 4) = make_uint2(lo, hi);
    }
}

// ---------------------------------------------------------------------------
// K1: mega kernel. Phase 1: conv MFMA. W fragments load DIRECTLY from global
// (Wb is 393 KB -> L2-resident; the old As tile was a pure pass-through copy).
// Bs (x tile) is double-buffered: next tile's global loads issue at loop top,
// pack+ds_write at loop bottom -> 1 barrier per k-step.
// Phase 2: scores MFMA + u1 LSE partials (unchanged).
// Block: 128 n x 256 d (full), 4 waves (wn x wd).
// ---------------------------------------------------------------------------
__global__ __launch_bounds__(256) void conv_mega(const float* __restrict__ x,
                                                 const unsigned short* __restrict__ Wb,
                                                 const float* __restrict__ bias,
                                                 const unsigned short* __restrict__ wnb,
                                                 float* __restrict__ xp,
                                                 float* __restrict__ inv_norm,
                                                 float* __restrict__ Z,
                                                 float2* __restrict__ u1p) {
    __shared__ unsigned Bs[2][128 * 17];   // x tile 128n x 32k, double-buffered
    __shared__ float ssq_s[128];
    __shared__ float invs_s[128];
    __shared__ unsigned xfs[128 * 33];     // xf quarter: 128n x 64d (bf16 pairs)
    __shared__ float2 upart_s[4][32];

    const int tid = threadIdx.x;
    const int lane = tid & 63;
    const int wid = tid >> 6;
    const int wn = wid & 1, wd = wid >> 1;
    const int b = blockIdx.y;
    const int n0 = blockIdx.x * 128;
    const int l15 = lane & 15, l4 = lane >> 4;
    const float* xb = x + (size_t)b * 768 * 4096;

    f32x4 acc[8][4];
#pragma unroll
    for (int i = 0; i < 8; ++i)
#pragma unroll
        for (int j = 0; j < 4; ++j) acc[i][j] = (f32x4){0.f, 0.f, 0.f, 0.f};

    // per-thread x staging coordinates: f = tid + i*256 -> n2 = tid&63 (const),
    // ch = wid + 4*i
    const int n2 = tid & 63;
    const float* xpt = xb + n0 + 2 * n2;
    float2 ga[4], gb[4];

    auto LOADX = [&](int k0) {
#pragma unroll
        for (int i = 0; i < 4; ++i) {
            const float* p = xpt + (size_t)(k0 + 2 * (wid + 4 * i)) * 4096;
            ga[i] = *(const float2*)p;
            gb[i] = *(const float2*)(p + 4096);
        }
    };
    auto STOREB = [&](int buf) {
#pragma unroll
        for (int i = 0; i < 4; ++i) {
            int ch = wid + 4 * i;
            Bs[buf][(2 * n2) * 17 + ch]     = pack_bf2(ga[i].x, gb[i].x);
            Bs[buf][(2 * n2 + 1) * 17 + ch] = pack_bf2(ga[i].y, gb[i].y);
        }
    };

    // ---------------- phase 1: conv ----------------
    LOADX(0);
    STOREB(0);
    __syncthreads();
    int cur = 0;
    for (int k0 = 0; k0 < 768; k0 += 32) {
        if (k0 + 32 < 768) LOADX(k0 + 32);    // prefetch next tile (regs)

        U8 af[8];                              // W fragments direct from L2
#pragma unroll
        for (int dt = 0; dt < 8; ++dt) {
            int row = wd * 128 + dt * 16 + l15;
            af[dt].q = *(const uint4*)(Wb + (size_t)row * 768 + k0 + l4 * 8);
        }
#pragma unroll
        for (int nt = 0; nt < 4; ++nt) {
            int col = wn * 64 + nt * 16 + l15;
            int base = col * 17 + l4 * 4;
            U8 bf;
            bf.u[0] = Bs[cur][base];     bf.u[1] = Bs[cur][base + 1];
            bf.u[2] = Bs[cur][base + 2]; bf.u[3] = Bs[cur][base + 3];
#pragma unroll
            for (int dt = 0; dt < 8; ++dt)
                acc[dt][nt] = __builtin_amdgcn_mfma_f32_16x16x32_bf16(
                    af[dt].v, bf.v, acc[dt][nt], 0, 0, 0);
        }
        if (k0 + 32 < 768) STOREB(cur ^ 1);   // write next tile to other buffer
        __syncthreads();
        cur ^= 1;
    }

    // epilogue: bias into acc, store xp, row sum-of-squares -> inv_norm
    float ssq[4] = {0.f, 0.f, 0.f, 0.f};
#pragma unroll
    for (int dt = 0; dt < 8; ++dt) {
        int d = wd * 128 + dt * 16 + l4 * 4;
        float4 bi = *(const float4*)(bias + d);
#pragma unroll
        for (int nt = 0; nt < 4; ++nt) {
            int n = n0 + wn * 64 + nt * 16 + l15;
            f32x4 o = acc[dt][nt];
            o.x += bi.x; o.y += bi.y; o.z += bi.z; o.w += bi.w;
            acc[dt][nt] = o;
            *(f32x4*)(xp + ((size_t)(b * 4096 + n)) * 256 + d) = o;
            ssq[nt] += o.x * o.x + o.y * o.y + o.z * o.z + o.w * o.w;
        }
    }
#pragma unroll
    for (int nt = 0; nt < 4; ++nt) {
        ssq[nt] += __shfl_xor(ssq[nt], 16);
        ssq[nt] += __shfl_xor(ssq[nt], 32);
    }
    if (wd == 0 && l4 == 0) {
#pragma unroll
        for (int nt = 0; nt < 4; ++nt) ssq_s[wn * 64 + nt * 16 + l15] = ssq[nt];
    }
    __syncthreads();
    if (wd == 1 && l4 == 0) {
#pragma unroll
        for (int nt = 0; nt < 4; ++nt) {
            int nl = wn * 64 + nt * 16 + l15;
            float inv = 1.0f / fmaxf(sqrtf(ssq[nt] + ssq_s[nl]), 1e-12f);
            invs_s[nl] = inv;
            inv_norm[b * 4096 + n0 + nl] = inv;
        }
    }

    // ---------------- phase 2: scores + u1 partials ----------------
    f32x4 accz[2][2];
#pragma unroll
    for (int i = 0; i < 2; ++i)
#pragma unroll
        for (int j = 0; j < 2; ++j) accz[i][j] = (f32x4){0.f, 0.f, 0.f, 0.f};

    for (int q = 0; q < 4; ++q) {
        __syncthreads();
        if (wd == (q >> 1)) {
#pragma unroll
            for (int dt4 = 0; dt4 < 4; ++dt4) {
                int dt = (q & 1) * 4 + dt4;
#pragma unroll
                for (int nt = 0; nt < 4; ++nt) {
                    int n = wn * 64 + nt * 16 + l15;
                    float inv = invs_s[n];
                    f32x4 a = acc[dt][nt];
                    int base = n * 33 + dt4 * 8 + l4 * 2;
                    xfs[base]     = pack_bf2(a.x * inv, a.y * inv);
                    xfs[base + 1] = pack_bf2(a.z * inv, a.w * inv);
                }
            }
        }
        __syncthreads();
#pragma unroll
        for (int s = 0; s < 2; ++s) {
            U8 wf[2];
#pragma unroll
            for (int mt = 0; mt < 2; ++mt)
                wf[mt].q = *(const uint4*)(wnb + (mt * 16 + l15) * 256 +
                                           q * 64 + s * 32 + l4 * 8);
#pragma unroll
            for (int sti = 0; sti < 2; ++sti) {
                int st = wid + sti * 4;
                int arow = (st * 16 + l15) * 33 + s * 16 + l4 * 4;
                U8 af;
                af.u[0] = xfs[arow]; af.u[1] = xfs[arow + 1];
                af.u[2] = xfs[arow + 2]; af.u[3] = xfs[arow + 3];
#pragma unroll
                for (int mt = 0; mt < 2; ++mt)
                    accz[sti][mt] = __builtin_amdgcn_mfma_f32_16x16x32_bf16(
                        af.v, wf[mt].v, accz[sti][mt], 0, 0, 0);
            }
        }
    }
    // scale by 1/EPS, write Z, emit u1 partials
#pragma unroll
    for (int sti = 0; sti < 2; ++sti)
#pragma unroll
        for (int mt = 0; mt < 2; ++mt) {
            accz[sti][mt].x *= 20.f; accz[sti][mt].y *= 20.f;
            accz[sti][mt].z *= 20.f; accz[sti][mt].w *= 20.f;
            int m = mt * 16 + l15;
            int st = wid + sti * 4;
            *(f32x4*)&Z[((size_t)(b * 32 + m)) * 4096 + n0 + st * 16 + l4 * 4] =
                accz[sti][mt];
        }
#pragma unroll
    for (int mt = 0; mt < 2; ++mt) {
        float v0[8] = {accz[0][mt].x, accz[0][mt].y, accz[0][mt].z, accz[0][mt].w,
                       accz[1][mt].x, accz[1][mt].y, accz[1][mt].z, accz[1][mt].w};
        float mx = v0[0];
#pragma unroll
        for (int i = 1; i < 8; ++i) mx = fmaxf(mx, v0[i]);
        float s = 0.f;
#pragma unroll
        for (int i = 0; i < 8; ++i) s += __expf(v0[i] - mx);
#pragma unroll
        for (int off = 16; off < 64; off <<= 1) {
            float omx = __shfl_xor(mx, off);
            float os = __shfl_xor(s, off);
            float nm = fmaxf(mx, omx);
            s = s * __expf(mx - nm) + os * __expf(omx - nm);
            mx = nm;
        }
        if (lane < 16) upart_s[wid][mt * 16 + lane] = make_float2(mx, s);
    }
    __syncthreads();
    if (wid == 0 && lane < 32) {
        float2 p = upart_s[0][lane];
        float mx = p.x, s = p.y;
#pragma unroll
        for (int w = 1; w < 4; ++w) {
            float2 qq = upart_s[w][lane];
            float nm = fmaxf(mx, qq.x);
            s = s * __expf(mx - nm) + qq.y * __expf(qq.x - nm);
            mx = nm;
        }
        u1p[((size_t)b * 32 + blockIdx.x) * 32 + lane] = make_float2(mx, s);
    }
}

// ---------------------------------------------------------------------------
// K2: fused sinkhorn step. Combines NIN chunk-partials -> u (LSE over n),
// computes v for this block's 256 n IN REGISTERS, then emits per-block
// u-partials for the NEXT u-update (max-butterfly + sum-butterfly per m).
// Replaces the old sink_v / sink_u pairs: Z is read ONCE per step.
// ---------------------------------------------------------------------------
template <int NIN>
__global__ __launch_bounds__(256) void sink_step(const float* __restrict__ Z,
                                                 const float2* __restrict__ up_in,
                                                 float2* __restrict__ up_out) {
    __shared__ float u_s[32];
    __shared__ float2 red_s[4][32];
    const int tid = threadIdx.x;
    const int lane = tid & 63, wid = tid >> 6;
    const int b = blockIdx.y;
    const int chunk = blockIdx.x;
    const int n = chunk * 256 + tid;

    if (tid < 32) {
        float2 p = up_in[((size_t)b * NIN) * 32 + tid];
        float mx = p.x, s = p.y;
#pragma unroll 4
        for (int t = 1; t < NIN; ++t) {
            float2 q = up_in[((size_t)b * NIN + t) * 32 + tid];
            float nm = fmaxf(mx, q.x);
            s = s * __expf(mx - nm) + q.y * __expf(q.x - nm);
            mx = nm;
        }
        u_s[tid] = NORM_C - (mx + __logf(s));
    }
    __syncthreads();

    float z[32];
#pragma unroll
    for (int m = 0; m < 32; ++m) z[m] = Z[((size_t)(b * 32 + m)) * 4096 + n];

    // v-update for this n
    float mx = z[0] + u_s[0];
#pragma unroll
    for (int m = 1; m < 32; ++m) mx = fmaxf(mx, z[m] + u_s[m]);
    float s = 0.f;
#pragma unroll
    for (int m = 0; m < 32; ++m) s += __expf(z[m] + u_s[m] - mx);
    float vv = NORM_C - (mx + __logf(s));

    // next-u partials: per m, LSE over this block's 256 n of (z+v)
#pragma unroll
    for (int m = 0; m < 32; ++m) {
        float val = z[m] + vv;
        float vmx = val;
#pragma unroll
        for (int off = 1; off < 64; off <<= 1) vmx = fmaxf(vmx, __shfl_xor(vmx, off));
        float e = __expf(val - vmx);
#pragma unroll
        for (int off = 1; off < 64; off <<= 1) e += __shfl_xor(e, off);
        if (lane == 0) red_s[wid][m] = make_float2(vmx, e);
    }
    __syncthreads();
    if (tid < 32) {
        float2 p = red_s[0][tid];
        float gm = p.x, gs = p.y;
#pragma unroll
        for (int w = 1; w < 4; ++w) {
            float2 q = red_s[w][tid];
            float nm = fmaxf(gm, q.x);
            gs = gs * __expf(gm - nm) + q.y * __expf(q.x - nm);
            gm = nm;
        }
        up_out[((size_t)b * 16 + chunk) * 32 + tid] = make_float2(gm, gs);
    }
}

// ---------------------------------------------------------------------------
// K4: v_tilde partials. u3 combined from u3 partials in prologue; v3 computed
// inline; raw Z chunk staged in LDS (read once instead of twice). Block:
// (chunk of 256 n x d-half 128, b). Thread: 4 d x 4 m.
// ---------------------------------------------------------------------------
__global__ __launch_bounds__(256) void vtilde_part_k(const float* __restrict__ xp,
                                                     const float* __restrict__ inv_norm,
                                                     const float* __restrict__ Z,
                                                     const float2* __restrict__ u3p,
                                                     float* __restrict__ part) {
    __shared__ float u_s[32];
    __shared__ float v3_s[256];
    __shared__ float inv_s[256];
    __shared__ float z_s[32 * 257];
    __shared__ float wt[64 * 36];
    const int tid = threadIdx.x;
    const int cx = blockIdx.x;
    const int chunk = cx >> 1, dh = cx & 1;
    const int b = blockIdx.y;
    const int n0 = chunk * 256;

    if (tid < 32) {
        float2 p = u3p[((size_t)b * 16) * 32 + tid];
        float gm = p.x, gs = p.y;
#pragma unroll
        for (int t = 1; t < 16; ++t) {
            float2 q = u3p[((size_t)b * 16 + t) * 32 + tid];
            float nm = fmaxf(gm, q.x);
            gs = gs * __expf(gm - nm) + q.y * __expf(q.x - nm);
            gm = nm;
        }
        u_s[tid] = NORM_C - (gm + __logf(gs));
    }
    __syncthreads();
    {
        int n = n0 + tid;
        float zr[32];
#pragma unroll
        for (int m = 0; m < 32; ++m) {
            zr[m] = Z[((size_t)(b * 32 + m)) * 4096 + n];
            z_s[m * 257 + tid] = zr[m];
        }
        float mx = zr[0] + u_s[0];
#pragma unroll
        for (int m = 1; m < 32; ++m) mx = fmaxf(mx, zr[m] + u_s[m]);
        float s = 0.f;
#pragma unroll
        for (int m = 0; m < 32; ++m) s += __expf(zr[m] + u_s[m] - mx);
        v3_s[tid] = NORM_C - (mx + __logf(s));
        inv_s[tid] = inv_norm[b * 4096 + n];
    }
    __syncthreads();

    const int dg = tid & 31, mq = tid >> 5;
    f32x4 acc[4];
#pragma unroll
    for (int j = 0; j < 4; ++j) acc[j] = (f32x4){0.f, 0.f, 0.f, 0.f};
    const float* xpb = xp + ((size_t)(b * 4096 + n0)) * 256 + dh * 128 + dg * 4;

    for (int t = 0; t < 4; ++t) {
#pragma unroll
        for (int i = 0; i < 8; ++i) {
            int e = tid + i * 256;
            int mW = e >> 6, nn = e & 63;
            int nl = t * 64 + nn;
            wt[nn * 36 + mW] =
                __expf(z_s[mW * 257 + nl] + u_s[mW] + v3_s[nl] - NORM_C) * inv_s[nl];
        }
        __syncthreads();
#pragma unroll 4
        for (int nn = 0; nn < 64; ++nn) {
            float4 xv = *(const float4*)(xpb + (size_t)(t * 64 + nn) * 256);
            float4 wv = *(const float4*)&wt[nn * 36 + mq * 4];
            acc[0].x += wv.x * xv.x; acc[0].y += wv.x * xv.y; acc[0].z += wv.x * xv.z; acc[0].w += wv.x * xv.w;
            acc[1].x += wv.y * xv.x; acc[1].y += wv.y * xv.y; acc[1].z += wv.y * xv.z; acc[1].w += wv.y * xv.w;
            acc[2].x += wv.z * xv.x; acc[2].y += wv.z * xv.y; acc[2].z += wv.z * xv.z; acc[2].w += wv.z * xv.w;
            acc[3].x += wv.w * xv.x; acc[3].y += wv.w * xv.y; acc[3].z += wv.w * xv.z; acc[3].w += wv.w * xv.w;
        }
        __syncthreads();
    }
#pragma unroll
    for (int j = 0; j < 4; ++j) {
        int m = mq * 4 + j;
        *(f32x4*)&part[((size_t)(b * 16 + chunk)) * 8192 + m * 256 + dh * 128 + dg * 4] = acc[j];
    }
}

// ---------------------------------------------------------------------------
// K5: reduce 16 chunk-partials -> v_tilde
// ---------------------------------------------------------------------------
__global__ __launch_bounds__(256) void vtilde_reduce(const float* __restrict__ part,
                                                     float* __restrict__ out_vt) {
    int o = blockIdx.x * 256 + threadIdx.x;
    int b = o >> 13, r = o & 8191;
    float s = 0.f;
#pragma unroll
    for (int c = 0; c < 16; ++c)
        s += part[((size_t)(b * 16 + c)) * 8192 + r];
    out_vt[o] = s;
}

// ---------------------------------------------------------------------------
extern "C" void kernel_launch(void* const* d_in, const int* in_sizes, int n_in,
                              void* d_out, int out_size, void* d_ws, size_t ws_size,
                              hipStream_t stream) {
    const float* x      = (const float*)d_in[0];
    const float* conv_w = (const float*)d_in[1];
    const float* conv_b = (const float*)d_in[2];
    const float* v_in   = (const float*)d_in[3];

    float* out_vt = (float*)d_out;                 // [16][32][256]
    float* out_xp = (float*)d_out + 131072;        // [16][4096][256]

    float* ws = (float*)d_ws;
    float*          inv_norm = ws;                                  // 65536
    unsigned short* Wb       = (unsigned short*)(ws + 65536);       // 196608 bf16
    unsigned short* wnb      = (unsigned short*)(ws + 163840);      // 8192 bf16
    float*          Zbuf     = ws + 167936;                         // 2097152
    float2*         u1p      = (float2*)(ws + 2265088);             // 16384 float2
    float2*         u2p      = (float2*)(ws + 2297856);             // 8192 float2
    float2*         u3p      = (float2*)(ws + 2314240);             // 8192 float2
    float*          part     = ws + 2330624;                        // 2097152

    w_prep<<<800, 64, 0, stream>>>(conv_w, v_in, Wb, wnb);
    conv_mega<<<dim3(32, 16), 256, 0, stream>>>(x, Wb, conv_b, wnb, out_xp,
                                                inv_norm, Zbuf, u1p);
    sink_step<32><<<dim3(16, 16), 256, 0, stream>>>(Zbuf, u1p, u2p);  // u1 -> v1 -> u2 partials
    sink_step<16><<<dim3(16, 16), 256, 0, stream>>>(Zbuf, u2p, u3p);  // u2 -> v2 -> u3 partials
    vtilde_part_k<<<dim3(32, 16), 256, 0, stream>>>(out_xp, inv_norm, Zbuf, u3p, part);
    vtilde_reduce<<<512, 256, 0, stream>>>(part, out_vt);
}

// Round 2
// 393.766 us; speedup vs baseline: 1.0537x; 1.0537x over previous
//
#include <hip/hip_runtime.h>
#include <math.h>

#define NORM_C (-8.3255483f)   /* -log(32+4096) */

typedef __attribute__((ext_vector_type(8))) short bf16x8;
typedef __attribute__((ext_vector_type(4))) float f32x4;

union U8 { uint4 q; unsigned u[4]; bf16x8 v; };

__device__ inline unsigned short f2bf_rne(float f) {
    unsigned u = __float_as_uint(f);
    unsigned r = u + 0x7fffu + ((u >> 16) & 1u);
    return (unsigned short)(r >> 16);
}
// pack two floats -> (bf16(hi)<<16)|bf16(lo)
__device__ inline unsigned pack_bf2(float lo, float hi) {
    unsigned a = __float_as_uint(lo) + 0x8000u;
    unsigned b = __float_as_uint(hi) + 0x8000u;
    return __builtin_amdgcn_perm(b, a, 0x07060302u);
}

// ---------------------------------------------------------------------------
// K0: fused prep. blocks 0..767: conv_w fp32->bf16 in MFMA-fragment-tiled
// layout Wbt[t][row][l4][8] (t = k/32, l4 = (k%32)/8) so that a wave's af
// fragment load is one contiguous 1KB block. blocks 768..799: normalize
// clusters v[32][256] -> bf16 (row-major, unchanged).
// ---------------------------------------------------------------------------
__global__ __launch_bounds__(64) void w_prep(const float* __restrict__ W,
                                             const float* __restrict__ v_in,
                                             unsigned short* __restrict__ Wbt,
                                             unsigned short* __restrict__ wnb) {
    const int bx = blockIdx.x, tid = threadIdx.x;
    if (bx < 768) {
        int i = (bx * 64 + tid) * 4;
        int row = i / 768;
        int k = i - row * 768;
        int t = k >> 5, q = (k >> 3) & 3, e = k & 7;  // e in {0,4}
        float4 w = *(const float4*)(W + i);
        unsigned lo = (unsigned)f2bf_rne(w.x) | ((unsigned)f2bf_rne(w.y) << 16);
        unsigned hi = (unsigned)f2bf_rne(w.z) | ((unsigned)f2bf_rne(w.w) << 16);
        *(uint2*)(Wbt + ((t * 256 + row) << 5) + q * 8 + e) = make_uint2(lo, hi);
    } else {
        int row = bx - 768;
        float4 v = *(const float4*)(v_in + row * 256 + tid * 4);
        float s = v.x * v.x + v.y * v.y + v.z * v.z + v.w * v.w;
#pragma unroll
        for (int off = 32; off > 0; off >>= 1) s += __shfl_xor(s, off);
        float inv = 1.0f / fmaxf(sqrtf(s), 1e-12f);
        unsigned lo = (unsigned)f2bf_rne(v.x * inv) | ((unsigned)f2bf_rne(v.y * inv) << 16);
        unsigned hi = (unsigned)f2bf_rne(v.z * inv) | ((unsigned)f2bf_rne(v.w * inv) << 16);
        *(uint2*)(wnb + row * 256 + tid * 4) = make_uint2(lo, hi);
    }
}

// ---------------------------------------------------------------------------
// K1: mega kernel, 64n x 256d tile, 4 waves (each wave: 64d quarter x 64n).
// Grid (64, 16) = 1024 blocks -> 4 blocks/CU; target <=128 VGPR -> 16 waves/CU.
// Phase 1: conv MFMA; W fragments coalesced direct from L2 (tiled layout);
// x tile double-buffered in LDS with depth-2 register pipeline (loads for
// tile k+2 issued one full k-step before their ds_write).
// Phase 2: scores MFMA over two 128-d halves + u1 LSE partials.
// ---------------------------------------------------------------------------
__global__ __launch_bounds__(256, 4) void conv_mega(const float* __restrict__ x,
                                                    const unsigned short* __restrict__ Wbt,
                                                    const float* __restrict__ bias,
                                                    const unsigned short* __restrict__ wnb,
                                                    float* __restrict__ xp,
                                                    float* __restrict__ inv_norm,
                                                    float* __restrict__ Z,
                                                    float2* __restrict__ u1p) {
    __shared__ unsigned Bs[2][64 * 17];   // x tile 64n x 32k, double-buffered
    __shared__ unsigned xf_s[64 * 65];    // xf half: 64n x 128d (bf16 pairs)
    __shared__ float ssq_s[4][64];
    __shared__ float invs_s[64];
    __shared__ float2 upart_s[4][32];

    const int tid = threadIdx.x;
    const int lane = tid & 63;
    const int wid = tid >> 6;            // wave = d-quarter (64 d)
    const int b = blockIdx.y;
    const int n0 = blockIdx.x * 64;
    const int l15 = lane & 15, l4 = lane >> 4;
    const float* xb = x + (size_t)b * 768 * 4096;

    f32x4 acc[4][4];
#pragma unroll
    for (int i = 0; i < 4; ++i)
#pragma unroll
        for (int j = 0; j < 4; ++j) acc[i][j] = (f32x4){0.f, 0.f, 0.f, 0.f};

    // x staging coords: n2 = n-pair, c8 = base channel-pair
    const int n2 = tid & 31, c8 = tid >> 5;
    const float* xpt = xb + n0 + 2 * n2;

    float2 gaA[2], gbA[2], gaB[2], gbB[2];

    auto LOADA = [&](int k0) {
#pragma unroll
        for (int i = 0; i < 2; ++i) {
            const float* p = xpt + (size_t)(k0 + 2 * (c8 + 8 * i)) * 4096;
            gaA[i] = *(const float2*)p;
            gbA[i] = *(const float2*)(p + 4096);
        }
    };
    auto LOADB = [&](int k0) {
#pragma unroll
        for (int i = 0; i < 2; ++i) {
            const float* p = xpt + (size_t)(k0 + 2 * (c8 + 8 * i)) * 4096;
            gaB[i] = *(const float2*)p;
            gbB[i] = *(const float2*)(p + 4096);
        }
    };
    auto STOREA = [&](int buf) {
#pragma unroll
        for (int i = 0; i < 2; ++i) {
            int ch = c8 + 8 * i;
            Bs[buf][(2 * n2) * 17 + ch]     = pack_bf2(gaA[i].x, gbA[i].x);
            Bs[buf][(2 * n2 + 1) * 17 + ch] = pack_bf2(gaA[i].y, gbA[i].y);
        }
    };
    auto STOREB = [&](int buf) {
#pragma unroll
        for (int i = 0; i < 2; ++i) {
            int ch = c8 + 8 * i;
            Bs[buf][(2 * n2) * 17 + ch]     = pack_bf2(gaB[i].x, gbB[i].x);
            Bs[buf][(2 * n2 + 1) * 17 + ch] = pack_bf2(gaB[i].y, gbB[i].y);
        }
    };
    auto MFMA_STEP = [&](int t, int buf) {
        U8 af[4];
#pragma unroll
        for (int dt = 0; dt < 4; ++dt)      // contiguous 1KB per wave from L2
            af[dt].q = *(const uint4*)(Wbt +
                ((t * 256 + wid * 64 + dt * 16 + l15) << 5) + l4 * 8);
#pragma unroll
        for (int nt = 0; nt < 4; ++nt) {
            int base = (nt * 16 + l15) * 17 + l4 * 4;
            U8 bf;
            bf.u[0] = Bs[buf][base];     bf.u[1] = Bs[buf][base + 1];
            bf.u[2] = Bs[buf][base + 2]; bf.u[3] = Bs[buf][base + 3];
#pragma unroll
            for (int dt = 0; dt < 4; ++dt)
                acc[dt][nt] = __builtin_amdgcn_mfma_f32_16x16x32_bf16(
                    af[dt].v, bf.v, acc[dt][nt], 0, 0, 0);
        }
    };

    // ---------------- phase 1: conv, depth-2 pipeline ----------------
    LOADA(0);
    STOREA(0);            // prologue: unavoidable vmcnt wait (once)
    LOADB(32);            // tile 1 -> regs B
    __syncthreads();
    for (int t = 0; t < 24; t += 2) {
        // even half: compute tile t (buf0); write tile t+1 (regs B -> buf1);
        // issue loads for tile t+2 (regs A)
        if (t + 2 < 24) LOADA((t + 2) * 32);
        MFMA_STEP(t, 0);
        STOREB(1);        // consumes loads issued one full k-step ago
        __syncthreads();
        // odd half: compute tile t+1 (buf1); write tile t+2 (regs A -> buf0);
        // issue loads for tile t+3 (regs B)
        if (t + 3 < 24) LOADB((t + 3) * 32);
        MFMA_STEP(t + 1, 1);
        if (t + 2 < 24) STOREA(0);
        __syncthreads();
    }

    // epilogue: bias into acc, store xp, row sum-of-squares -> inv_norm
    float ssq[4] = {0.f, 0.f, 0.f, 0.f};
#pragma unroll
    for (int dt = 0; dt < 4; ++dt) {
        int d = wid * 64 + dt * 16 + l4 * 4;
        float4 bi = *(const float4*)(bias + d);
#pragma unroll
        for (int nt = 0; nt < 4; ++nt) {
            int n = n0 + nt * 16 + l15;
            f32x4 o = acc[dt][nt];
            o.x += bi.x; o.y += bi.y; o.z += bi.z; o.w += bi.w;
            acc[dt][nt] = o;
            *(f32x4*)(xp + ((size_t)(b * 4096 + n)) * 256 + d) = o;
            ssq[nt] += o.x * o.x + o.y * o.y + o.z * o.z + o.w * o.w;
        }
    }
#pragma unroll
    for (int nt = 0; nt < 4; ++nt) {
        ssq[nt] += __shfl_xor(ssq[nt], 16);
        ssq[nt] += __shfl_xor(ssq[nt], 32);
    }
    if (l4 == 0) {
#pragma unroll
        for (int nt = 0; nt < 4; ++nt) ssq_s[wid][nt * 16 + l15] = ssq[nt];
    }
    __syncthreads();
    if (tid < 64) {
        float s = ssq_s[0][tid] + ssq_s[1][tid] + ssq_s[2][tid] + ssq_s[3][tid];
        float inv = 1.0f / fmaxf(sqrtf(s), 1e-12f);
        invs_s[tid] = inv;
        inv_norm[b * 4096 + n0 + tid] = inv;
    }

    // ---------------- phase 2: scores + u1 partials ----------------
    f32x4 accz[2];
    accz[0] = (f32x4){0.f, 0.f, 0.f, 0.f};
    accz[1] = (f32x4){0.f, 0.f, 0.f, 0.f};

    for (int h = 0; h < 2; ++h) {
        __syncthreads();
        if ((wid >> 1) == h) {           // 2 waves stage their d-quarters
            int qh = wid & 1;
#pragma unroll
            for (int dt = 0; dt < 4; ++dt)
#pragma unroll
                for (int nt = 0; nt < 4; ++nt) {
                    int n = nt * 16 + l15;
                    float inv = invs_s[n];
                    f32x4 a = acc[dt][nt];
                    int base = n * 65 + qh * 32 + dt * 8 + l4 * 2;
                    xf_s[base]     = pack_bf2(a.x * inv, a.y * inv);
                    xf_s[base + 1] = pack_bf2(a.z * inv, a.w * inv);
                }
        }
        __syncthreads();
#pragma unroll
        for (int s = 0; s < 4; ++s) {
            U8 wf[2];
#pragma unroll
            for (int mt = 0; mt < 2; ++mt)
                wf[mt].q = *(const uint4*)(wnb + (mt * 16 + l15) * 256 +
                                           h * 128 + s * 32 + l4 * 8);
            int arow = (wid * 16 + l15) * 65 + s * 16 + l4 * 4;
            U8 af2;
            af2.u[0] = xf_s[arow];     af2.u[1] = xf_s[arow + 1];
            af2.u[2] = xf_s[arow + 2]; af2.u[3] = xf_s[arow + 3];
#pragma unroll
            for (int mt = 0; mt < 2; ++mt)
                accz[mt] = __builtin_amdgcn_mfma_f32_16x16x32_bf16(
                    af2.v, wf[mt].v, accz[mt], 0, 0, 0);
        }
    }
    // scale by 1/EPS, write Z, emit u1 partials
#pragma unroll
    for (int mt = 0; mt < 2; ++mt) {
        accz[mt].x *= 20.f; accz[mt].y *= 20.f;
        accz[mt].z *= 20.f; accz[mt].w *= 20.f;
        int m = mt * 16 + l15;
        *(f32x4*)&Z[((size_t)(b * 32 + m)) * 4096 + n0 + wid * 16 + l4 * 4] =
            accz[mt];
    }
#pragma unroll
    for (int mt = 0; mt < 2; ++mt) {
        f32x4 vz = accz[mt];
        float mx = fmaxf(fmaxf(vz.x, vz.y), fmaxf(vz.z, vz.w));
        float s = __expf(vz.x - mx) + __expf(vz.y - mx) +
                  __expf(vz.z - mx) + __expf(vz.w - mx);
#pragma unroll
        for (int off = 16; off < 64; off <<= 1) {
            float omx = __shfl_xor(mx, off);
            float os = __shfl_xor(s, off);
            float nm = fmaxf(mx, omx);
            s = s * __expf(mx - nm) + os * __expf(omx - nm);
            mx = nm;
        }
        if (lane < 16) upart_s[wid][mt * 16 + lane] = make_float2(mx, s);
    }
    __syncthreads();
    if (wid == 0 && lane < 32) {
        float2 p = upart_s[0][lane];
        float mx = p.x, s = p.y;
#pragma unroll
        for (int w = 1; w < 4; ++w) {
            float2 qq = upart_s[w][lane];
            float nm = fmaxf(mx, qq.x);
            s = s * __expf(mx - nm) + qq.y * __expf(qq.x - nm);
            mx = nm;
        }
        u1p[((size_t)b * 64 + blockIdx.x) * 32 + lane] = make_float2(mx, s);
    }
}

// ---------------------------------------------------------------------------
// K2: fused sinkhorn step. Combines NIN chunk-partials -> u (LSE over n),
// computes v for this block's 256 n IN REGISTERS, then emits per-block
// u-partials for the NEXT u-update. Z is read ONCE per step.
// ---------------------------------------------------------------------------
template <int NIN>
__global__ __launch_bounds__(256) void sink_step(const float* __restrict__ Z,
                                                 const float2* __restrict__ up_in,
                                                 float2* __restrict__ up_out) {
    __shared__ float u_s[32];
    __shared__ float2 red_s[4][32];
    const int tid = threadIdx.x;
    const int lane = tid & 63, wid = tid >> 6;
    const int b = blockIdx.y;
    const int chunk = blockIdx.x;
    const int n = chunk * 256 + tid;

    if (tid < 32) {
        float2 p = up_in[((size_t)b * NIN) * 32 + tid];
        float mx = p.x, s = p.y;
#pragma unroll 4
        for (int t = 1; t < NIN; ++t) {
            float2 q = up_in[((size_t)b * NIN + t) * 32 + tid];
            float nm = fmaxf(mx, q.x);
            s = s * __expf(mx - nm) + q.y * __expf(q.x - nm);
            mx = nm;
        }
        u_s[tid] = NORM_C - (mx + __logf(s));
    }
    __syncthreads();

    float z[32];
#pragma unroll
    for (int m = 0; m < 32; ++m) z[m] = Z[((size_t)(b * 32 + m)) * 4096 + n];

    // v-update for this n
    float mx = z[0] + u_s[0];
#pragma unroll
    for (int m = 1; m < 32; ++m) mx = fmaxf(mx, z[m] + u_s[m]);
    float s = 0.f;
#pragma unroll
    for (int m = 0; m < 32; ++m) s += __expf(z[m] + u_s[m] - mx);
    float vv = NORM_C - (mx + __logf(s));

    // next-u partials: per m, LSE over this block's 256 n of (z+v)
#pragma unroll
    for (int m = 0; m < 32; ++m) {
        float val = z[m] + vv;
        float vmx = val;
#pragma unroll
        for (int off = 1; off < 64; off <<= 1) vmx = fmaxf(vmx, __shfl_xor(vmx, off));
        float e = __expf(val - vmx);
#pragma unroll
        for (int off = 1; off < 64; off <<= 1) e += __shfl_xor(e, off);
        if (lane == 0) red_s[wid][m] = make_float2(vmx, e);
    }
    __syncthreads();
    if (tid < 32) {
        float2 p = red_s[0][tid];
        float gm = p.x, gs = p.y;
#pragma unroll
        for (int w = 1; w < 4; ++w) {
            float2 q = red_s[w][tid];
            float nm = fmaxf(gm, q.x);
            gs = gs * __expf(gm - nm) + q.y * __expf(q.x - nm);
            gm = nm;
        }
        up_out[((size_t)b * 16 + chunk) * 32 + tid] = make_float2(gm, gs);
    }
}

// ---------------------------------------------------------------------------
// K4: v_tilde partials. u3 combined from u3 partials in prologue; v3 computed
// inline; raw Z chunk staged in LDS (read once instead of twice). Block:
// (chunk of 256 n x d-half 128, b). Thread: 4 d x 4 m.
// ---------------------------------------------------------------------------
__global__ __launch_bounds__(256) void vtilde_part_k(const float* __restrict__ xp,
                                                     const float* __restrict__ inv_norm,
                                                     const float* __restrict__ Z,
                                                     const float2* __restrict__ u3p,
                                                     float* __restrict__ part) {
    __shared__ float u_s[32];
    __shared__ float v3_s[256];
    __shared__ float inv_s[256];
    __shared__ float z_s[32 * 257];
    __shared__ float wt[64 * 36];
    const int tid = threadIdx.x;
    const int cx = blockIdx.x;
    const int chunk = cx >> 1, dh = cx & 1;
    const int b = blockIdx.y;
    const int n0 = chunk * 256;

    if (tid < 32) {
        float2 p = u3p[((size_t)b * 16) * 32 + tid];
        float gm = p.x, gs = p.y;
#pragma unroll
        for (int t = 1; t < 16; ++t) {
            float2 q = u3p[((size_t)b * 16 + t) * 32 + tid];
            float nm = fmaxf(gm, q.x);
            gs = gs * __expf(gm - nm) + q.y * __expf(q.x - nm);
            gm = nm;
        }
        u_s[tid] = NORM_C - (gm + __logf(gs));
    }
    __syncthreads();
    {
        int n = n0 + tid;
        float zr[32];
#pragma unroll
        for (int m = 0; m < 32; ++m) {
            zr[m] = Z[((size_t)(b * 32 + m)) * 4096 + n];
            z_s[m * 257 + tid] = zr[m];
        }
        float mx = zr[0] + u_s[0];
#pragma unroll
        for (int m = 1; m < 32; ++m) mx = fmaxf(mx, zr[m] + u_s[m]);
        float s = 0.f;
#pragma unroll
        for (int m = 0; m < 32; ++m) s += __expf(zr[m] + u_s[m] - mx);
        v3_s[tid] = NORM_C - (mx + __logf(s));
        inv_s[tid] = inv_norm[b * 4096 + n];
    }
    __syncthreads();

    const int dg = tid & 31, mq = tid >> 5;
    f32x4 acc[4];
#pragma unroll
    for (int j = 0; j < 4; ++j) acc[j] = (f32x4){0.f, 0.f, 0.f, 0.f};
    const float* xpb = xp + ((size_t)(b * 4096 + n0)) * 256 + dh * 128 + dg * 4;

    for (int t = 0; t < 4; ++t) {
#pragma unroll
        for (int i = 0; i < 8; ++i) {
            int e = tid + i * 256;
            int mW = e >> 6, nn = e & 63;
            int nl = t * 64 + nn;
            wt[nn * 36 + mW] =
                __expf(z_s[mW * 257 + nl] + u_s[mW] + v3_s[nl] - NORM_C) * inv_s[nl];
        }
        __syncthreads();
#pragma unroll 4
        for (int nn = 0; nn < 64; ++nn) {
            float4 xv = *(const float4*)(xpb + (size_t)(t * 64 + nn) * 256);
            float4 wv = *(const float4*)&wt[nn * 36 + mq * 4];
            acc[0].x += wv.x * xv.x; acc[0].y += wv.x * xv.y; acc[0].z += wv.x * xv.z; acc[0].w += wv.x * xv.w;
            acc[1].x += wv.y * xv.x; acc[1].y += wv.y * xv.y; acc[1].z += wv.y * xv.z; acc[1].w += wv.y * xv.w;
            acc[2].x += wv.z * xv.x; acc[2].y += wv.z * xv.y; acc[2].z += wv.z * xv.z; acc[2].w += wv.z * xv.w;
            acc[3].x += wv.w * xv.x; acc[3].y += wv.w * xv.y; acc[3].z += wv.w * xv.z; acc[3].w += wv.w * xv.w;
        }
        __syncthreads();
    }
#pragma unroll
    for (int j = 0; j < 4; ++j) {
        int m = mq * 4 + j;
        *(f32x4*)&part[((size_t)(b * 16 + chunk)) * 8192 + m * 256 + dh * 128 + dg * 4] = acc[j];
    }
}

// ---------------------------------------------------------------------------
// K5: reduce 16 chunk-partials -> v_tilde
// ---------------------------------------------------------------------------
__global__ __launch_bounds__(256) void vtilde_reduce(const float* __restrict__ part,
                                                     float* __restrict__ out_vt) {
    int o = blockIdx.x * 256 + threadIdx.x;
    int b = o >> 13, r = o & 8191;
    float s = 0.f;
#pragma unroll
    for (int c = 0; c < 16; ++c)
        s += part[((size_t)(b * 16 + c)) * 8192 + r];
    out_vt[o] = s;
}

// ---------------------------------------------------------------------------
extern "C" void kernel_launch(void* const* d_in, const int* in_sizes, int n_in,
                              void* d_out, int out_size, void* d_ws, size_t ws_size,
                              hipStream_t stream) {
    const float* x      = (const float*)d_in[0];
    const float* conv_w = (const float*)d_in[1];
    const float* conv_b = (const float*)d_in[2];
    const float* v_in   = (const float*)d_in[3];

    float* out_vt = (float*)d_out;                 // [16][32][256]
    float* out_xp = (float*)d_out + 131072;        // [16][4096][256]

    float* ws = (float*)d_ws;
    float*          inv_norm = ws;                                  // 65536 f
    unsigned short* Wbt      = (unsigned short*)(ws + 65536);       // 196608 bf16
    unsigned short* wnb      = (unsigned short*)(ws + 163840);      // 8192 bf16
    float*          Zbuf     = ws + 167936;                         // 2097152 f
    float*          part     = ws + 2265088;                        // 2097152 f
    // u1p aliases the part region: written by conv_mega, fully consumed by
    // sink_step<64> BEFORE vtilde_part_k writes part. 64*32*16 float2 fits.
    float2*         u1p      = (float2*)part;
    float2*         u2p      = (float2*)(ws + 4362240);             // 8192 float2
    float2*         u3p      = (float2*)(ws + 4378624);             // 8192 float2

    w_prep<<<800, 64, 0, stream>>>(conv_w, v_in, Wbt, wnb);
    conv_mega<<<dim3(64, 16), 256, 0, stream>>>(x, Wbt, conv_b, wnb, out_xp,
                                                inv_norm, Zbuf, u1p);
    sink_step<64><<<dim3(16, 16), 256, 0, stream>>>(Zbuf, u1p, u2p);  // u1 -> v1 -> u2 partials
    sink_step<16><<<dim3(16, 16), 256, 0, stream>>>(Zbuf, u2p, u3p);  // u2 -> v2 -> u3 partials
    vtilde_part_k<<<dim3(32, 16), 256, 0, stream>>>(out_xp, inv_norm, Zbuf, u3p, part);
    vtilde_reduce<<<512, 256, 0, stream>>>(part, out_vt);
}

// Round 3
// 392.317 us; speedup vs baseline: 1.0576x; 1.0037x over previous
//
#include <hip/hip_runtime.h>
#include <math.h>

#define NORM_C (-8.3255483f)   /* -log(32+4096) */

typedef __attribute__((ext_vector_type(8))) short bf16x8;
typedef __attribute__((ext_vector_type(4))) float f32x4;

union U8 { uint4 q; unsigned u[4]; bf16x8 v; };

__device__ inline unsigned short f2bf_rne(float f) {
    unsigned u = __float_as_uint(f);
    unsigned r = u + 0x7fffu + ((u >> 16) & 1u);
    return (unsigned short)(r >> 16);
}
// pack two floats -> (bf16(hi)<<16)|bf16(lo)
__device__ inline unsigned pack_bf2(float lo, float hi) {
    unsigned a = __float_as_uint(lo) + 0x8000u;
    unsigned b = __float_as_uint(hi) + 0x8000u;
    return __builtin_amdgcn_perm(b, a, 0x07060302u);
}

// ---------------------------------------------------------------------------
// K0: fused prep. blocks 0..767: conv_w fp32->bf16 (row-major). blocks
// 768..799: normalize clusters v[32][256] -> bf16.  (round-0 version)
// ---------------------------------------------------------------------------
__global__ __launch_bounds__(64) void w_prep(const float* __restrict__ W,
                                             const float* __restrict__ v_in,
                                             unsigned short* __restrict__ Wb,
                                             unsigned short* __restrict__ wnb) {
    const int bx = blockIdx.x, tid = threadIdx.x;
    if (bx < 768) {
        int i = (bx * 64 + tid) * 4;
        float4 w = *(const float4*)(W + i);
        unsigned lo = (unsigned)f2bf_rne(w.x) | ((unsigned)f2bf_rne(w.y) << 16);
        unsigned hi = (unsigned)f2bf_rne(w.z) | ((unsigned)f2bf_rne(w.w) << 16);
        *(uint2*)(Wb + i) = make_uint2(lo, hi);
    } else {
        int row = bx - 768;
        float4 v = *(const float4*)(v_in + row * 256 + tid * 4);
        float s = v.x * v.x + v.y * v.y + v.z * v.z + v.w * v.w;
#pragma unroll
        for (int off = 32; off > 0; off >>= 1) s += __shfl_xor(s, off);
        float inv = 1.0f / fmaxf(sqrtf(s), 1e-12f);
        unsigned lo = (unsigned)f2bf_rne(v.x * inv) | ((unsigned)f2bf_rne(v.y * inv) << 16);
        unsigned hi = (unsigned)f2bf_rne(v.z * inv) | ((unsigned)f2bf_rne(v.w * inv) << 16);
        *(uint2*)(wnb + row * 256 + tid * 4) = make_uint2(lo, hi);
    }
}

// ---------------------------------------------------------------------------
// K1: mega kernel (round-0 proven structure). Phase 1: conv MFMA (W bf16 x
// x bf16 -> xp fp32 + inv_norm), As/Bs LDS-staged, 2 barriers per k-step.
// Phase 2: scores MFMA (xf bf16 x w bf16 -> Z fp32) + u1 LSE partials.
// Block: 128 n x 256 d (full), 4 waves (wn x wd).
// ---------------------------------------------------------------------------
__global__ __launch_bounds__(256) void conv_mega(const float* __restrict__ x,
                                                 const unsigned short* __restrict__ Wb,
                                                 const float* __restrict__ bias,
                                                 const unsigned short* __restrict__ wnb,
                                                 float* __restrict__ xp,
                                                 float* __restrict__ inv_norm,
                                                 float* __restrict__ Z,
                                                 float2* __restrict__ u1p) {
    __shared__ unsigned As[256 * 20];    // W tile 256d x 32k
    __shared__ unsigned Bs[128 * 17];    // x tile 128n x 32k
    __shared__ float ssq_s[128];
    __shared__ float invs_s[128];
    __shared__ unsigned xfs[128 * 33];   // xf quarter: 128n x 64d (bf16 pairs)
    __shared__ float2 upart_s[4][32];

    const int tid = threadIdx.x;
    const int lane = tid & 63;
    const int wid = tid >> 6;
    const int wn = wid & 1, wd = wid >> 1;
    const int b = blockIdx.y;
    const int n0 = blockIdx.x * 128;
    const int l15 = lane & 15, l4 = lane >> 4;
    const float* xb = x + (size_t)b * 768 * 4096;

    f32x4 acc[8][4];
#pragma unroll
    for (int i = 0; i < 8; ++i)
#pragma unroll
        for (int j = 0; j < 4; ++j) acc[i][j] = (f32x4){0.f, 0.f, 0.f, 0.f};

    // ---------------- phase 1: conv ----------------
    for (int k0 = 0; k0 < 768; k0 += 32) {
        __syncthreads();
#pragma unroll
        for (int i = 0; i < 4; ++i) {
            int f = tid + i * 256;
            int dd = f >> 2, c8 = f & 3;
            uint4 w = *(const uint4*)(Wb + (size_t)dd * 768 + k0 + c8 * 8);
            *(uint4*)&As[dd * 20 + c8 * 4] = w;
        }
#pragma unroll
        for (int i = 0; i < 4; ++i) {
            int f = tid + i * 256;
            int n2 = f & 63, ch = f >> 6;
            const float* p = xb + (size_t)(k0 + 2 * ch) * 4096 + n0 + 2 * n2;
            float2 g0 = *(const float2*)p;
            float2 g1 = *(const float2*)(p + 4096);
            Bs[(2 * n2) * 17 + ch] = pack_bf2(g0.x, g1.x);
            Bs[(2 * n2 + 1) * 17 + ch] = pack_bf2(g0.y, g1.y);
        }
        __syncthreads();

        U8 af[8];
#pragma unroll
        for (int dt = 0; dt < 8; ++dt) {
            int row = wd * 128 + dt * 16 + l15;
            af[dt].q = *(uint4*)&As[row * 20 + l4 * 4];
        }
#pragma unroll
        for (int nt = 0; nt < 4; ++nt) {
            int col = wn * 64 + nt * 16 + l15;
            int base = col * 17 + l4 * 4;
            U8 bf;
            bf.u[0] = Bs[base]; bf.u[1] = Bs[base + 1];
            bf.u[2] = Bs[base + 2]; bf.u[3] = Bs[base + 3];
#pragma unroll
            for (int dt = 0; dt < 8; ++dt)
                acc[dt][nt] = __builtin_amdgcn_mfma_f32_16x16x32_bf16(
                    af[dt].v, bf.v, acc[dt][nt], 0, 0, 0);
        }
    }

    // epilogue: bias into acc, store xp, row sum-of-squares -> inv_norm
    float ssq[4] = {0.f, 0.f, 0.f, 0.f};
#pragma unroll
    for (int dt = 0; dt < 8; ++dt) {
        int d = wd * 128 + dt * 16 + l4 * 4;
        float4 bi = *(const float4*)(bias + d);
#pragma unroll
        for (int nt = 0; nt < 4; ++nt) {
            int n = n0 + wn * 64 + nt * 16 + l15;
            f32x4 o = acc[dt][nt];
            o.x += bi.x; o.y += bi.y; o.z += bi.z; o.w += bi.w;
            acc[dt][nt] = o;
            *(f32x4*)(xp + ((size_t)(b * 4096 + n)) * 256 + d) = o;
            ssq[nt] += o.x * o.x + o.y * o.y + o.z * o.z + o.w * o.w;
        }
    }
#pragma unroll
    for (int nt = 0; nt < 4; ++nt) {
        ssq[nt] += __shfl_xor(ssq[nt], 16);
        ssq[nt] += __shfl_xor(ssq[nt], 32);
    }
    if (wd == 0 && l4 == 0) {
#pragma unroll
        for (int nt = 0; nt < 4; ++nt) ssq_s[wn * 64 + nt * 16 + l15] = ssq[nt];
    }
    __syncthreads();
    if (wd == 1 && l4 == 0) {
#pragma unroll
        for (int nt = 0; nt < 4; ++nt) {
            int nl = wn * 64 + nt * 16 + l15;
            float inv = 1.0f / fmaxf(sqrtf(ssq[nt] + ssq_s[nl]), 1e-12f);
            invs_s[nl] = inv;
            inv_norm[b * 4096 + n0 + nl] = inv;
        }
    }

    // ---------------- phase 2: scores + u1 partials ----------------
    f32x4 accz[2][2];
#pragma unroll
    for (int i = 0; i < 2; ++i)
#pragma unroll
        for (int j = 0; j < 2; ++j) accz[i][j] = (f32x4){0.f, 0.f, 0.f, 0.f};

    for (int q = 0; q < 4; ++q) {
        __syncthreads();
        if (wd == (q >> 1)) {
#pragma unroll
            for (int dt4 = 0; dt4 < 4; ++dt4) {
                int dt = (q & 1) * 4 + dt4;
#pragma unroll
                for (int nt = 0; nt < 4; ++nt) {
                    int n = wn * 64 + nt * 16 + l15;
                    float inv = invs_s[n];
                    f32x4 a = acc[dt][nt];
                    int base = n * 33 + dt4 * 8 + l4 * 2;
                    xfs[base]     = pack_bf2(a.x * inv, a.y * inv);
                    xfs[base + 1] = pack_bf2(a.z * inv, a.w * inv);
                }
            }
        }
        __syncthreads();
#pragma unroll
        for (int s = 0; s < 2; ++s) {
            U8 wf[2];
#pragma unroll
            for (int mt = 0; mt < 2; ++mt)
                wf[mt].q = *(const uint4*)(wnb + (mt * 16 + l15) * 256 +
                                           q * 64 + s * 32 + l4 * 8);
#pragma unroll
            for (int sti = 0; sti < 2; ++sti) {
                int st = wid + sti * 4;
                int arow = (st * 16 + l15) * 33 + s * 16 + l4 * 4;
                U8 af;
                af.u[0] = xfs[arow]; af.u[1] = xfs[arow + 1];
                af.u[2] = xfs[arow + 2]; af.u[3] = xfs[arow + 3];
#pragma unroll
                for (int mt = 0; mt < 2; ++mt)
                    accz[sti][mt] = __builtin_amdgcn_mfma_f32_16x16x32_bf16(
                        af.v, wf[mt].v, accz[sti][mt], 0, 0, 0);
            }
        }
    }
    // scale by 1/EPS, write Z, emit u1 partials
#pragma unroll
    for (int sti = 0; sti < 2; ++sti)
#pragma unroll
        for (int mt = 0; mt < 2; ++mt) {
            accz[sti][mt].x *= 20.f; accz[sti][mt].y *= 20.f;
            accz[sti][mt].z *= 20.f; accz[sti][mt].w *= 20.f;
            int m = mt * 16 + l15;
            int st = wid + sti * 4;
            *(f32x4*)&Z[((size_t)(b * 32 + m)) * 4096 + n0 + st * 16 + l4 * 4] =
                accz[sti][mt];
        }
#pragma unroll
    for (int mt = 0; mt < 2; ++mt) {
        float v0[8] = {accz[0][mt].x, accz[0][mt].y, accz[0][mt].z, accz[0][mt].w,
                       accz[1][mt].x, accz[1][mt].y, accz[1][mt].z, accz[1][mt].w};
        float mx = v0[0];
#pragma unroll
        for (int i = 1; i < 8; ++i) mx = fmaxf(mx, v0[i]);
        float s = 0.f;
#pragma unroll
        for (int i = 0; i < 8; ++i) s += __expf(v0[i] - mx);
#pragma unroll
        for (int off = 16; off < 64; off <<= 1) {
            float omx = __shfl_xor(mx, off);
            float os = __shfl_xor(s, off);
            float nm = fmaxf(mx, omx);
            s = s * __expf(mx - nm) + os * __expf(omx - nm);
            mx = nm;
        }
        if (lane < 16) upart_s[wid][mt * 16 + lane] = make_float2(mx, s);
    }
    __syncthreads();
    if (wid == 0 && lane < 32) {
        float2 p = upart_s[0][lane];
        float mx = p.x, s = p.y;
#pragma unroll
        for (int w = 1; w < 4; ++w) {
            float2 qq = upart_s[w][lane];
            float nm = fmaxf(mx, qq.x);
            s = s * __expf(mx - nm) + qq.y * __expf(qq.x - nm);
            mx = nm;
        }
        u1p[((size_t)b * 32 + blockIdx.x) * 32 + lane] = make_float2(mx, s);
    }
}

// ---------------------------------------------------------------------------
// K2: fused sinkhorn step. Combines NIN chunk-partials -> u (LSE over n),
// computes v for this block's 256 n IN REGISTERS, then emits per-block
// u-partials for the NEXT u-update. Z is read ONCE per step.
// ---------------------------------------------------------------------------
template <int NIN>
__global__ __launch_bounds__(256) void sink_step(const float* __restrict__ Z,
                                                 const float2* __restrict__ up_in,
                                                 float2* __restrict__ up_out) {
    __shared__ float u_s[32];
    __shared__ float2 red_s[4][32];
    const int tid = threadIdx.x;
    const int lane = tid & 63, wid = tid >> 6;
    const int b = blockIdx.y;
    const int chunk = blockIdx.x;
    const int n = chunk * 256 + tid;

    if (tid < 32) {
        float2 p = up_in[((size_t)b * NIN) * 32 + tid];
        float mx = p.x, s = p.y;
#pragma unroll 4
        for (int t = 1; t < NIN; ++t) {
            float2 q = up_in[((size_t)b * NIN + t) * 32 + tid];
            float nm = fmaxf(mx, q.x);
            s = s * __expf(mx - nm) + q.y * __expf(q.x - nm);
            mx = nm;
        }
        u_s[tid] = NORM_C - (mx + __logf(s));
    }
    __syncthreads();

    float z[32];
#pragma unroll
    for (int m = 0; m < 32; ++m) z[m] = Z[((size_t)(b * 32 + m)) * 4096 + n];

    // v-update for this n
    float mx = z[0] + u_s[0];
#pragma unroll
    for (int m = 1; m < 32; ++m) mx = fmaxf(mx, z[m] + u_s[m]);
    float s = 0.f;
#pragma unroll
    for (int m = 0; m < 32; ++m) s += __expf(z[m] + u_s[m] - mx);
    float vv = NORM_C - (mx + __logf(s));

    // next-u partials: per m, LSE over this block's 256 n of (z+v)
#pragma unroll
    for (int m = 0; m < 32; ++m) {
        float val = z[m] + vv;
        float vmx = val;
#pragma unroll
        for (int off = 1; off < 64; off <<= 1) vmx = fmaxf(vmx, __shfl_xor(vmx, off));
        float e = __expf(val - vmx);
#pragma unroll
        for (int off = 1; off < 64; off <<= 1) e += __shfl_xor(e, off);
        if (lane == 0) red_s[wid][m] = make_float2(vmx, e);
    }
    __syncthreads();
    if (tid < 32) {
        float2 p = red_s[0][tid];
        float gm = p.x, gs = p.y;
#pragma unroll
        for (int w = 1; w < 4; ++w) {
            float2 q = red_s[w][tid];
            float nm = fmaxf(gm, q.x);
            gs = gs * __expf(gm - nm) + q.y * __expf(q.x - nm);
            gm = nm;
        }
        up_out[((size_t)b * 16 + chunk) * 32 + tid] = make_float2(gm, gs);
    }
}

// ---------------------------------------------------------------------------
// K4: v_tilde partials. u3 combined from u3 partials in prologue; v3 computed
// inline; raw Z chunk staged in LDS (read once instead of twice). Block:
// (chunk of 256 n x d-half 128, b). Thread: 4 d x 4 m.
// ---------------------------------------------------------------------------
__global__ __launch_bounds__(256) void vtilde_part_k(const float* __restrict__ xp,
                                                     const float* __restrict__ inv_norm,
                                                     const float* __restrict__ Z,
                                                     const float2* __restrict__ u3p,
                                                     float* __restrict__ part) {
    __shared__ float u_s[32];
    __shared__ float v3_s[256];
    __shared__ float inv_s[256];
    __shared__ float z_s[32 * 257];
    __shared__ float wt[64 * 36];
    const int tid = threadIdx.x;
    const int cx = blockIdx.x;
    const int chunk = cx >> 1, dh = cx & 1;
    const int b = blockIdx.y;
    const int n0 = chunk * 256;

    if (tid < 32) {
        float2 p = u3p[((size_t)b * 16) * 32 + tid];
        float gm = p.x, gs = p.y;
#pragma unroll
        for (int t = 1; t < 16; ++t) {
            float2 q = u3p[((size_t)b * 16 + t) * 32 + tid];
            float nm = fmaxf(gm, q.x);
            gs = gs * __expf(gm - nm) + q.y * __expf(q.x - nm);
            gm = nm;
        }
        u_s[tid] = NORM_C - (gm + __logf(gs));
    }
    __syncthreads();
    {
        int n = n0 + tid;
        float zr[32];
#pragma unroll
        for (int m = 0; m < 32; ++m) {
            zr[m] = Z[((size_t)(b * 32 + m)) * 4096 + n];
            z_s[m * 257 + tid] = zr[m];
        }
        float mx = zr[0] + u_s[0];
#pragma unroll
        for (int m = 1; m < 32; ++m) mx = fmaxf(mx, zr[m] + u_s[m]);
        float s = 0.f;
#pragma unroll
        for (int m = 0; m < 32; ++m) s += __expf(zr[m] + u_s[m] - mx);
        v3_s[tid] = NORM_C - (mx + __logf(s));
        inv_s[tid] = inv_norm[b * 4096 + n];
    }
    __syncthreads();

    const int dg = tid & 31, mq = tid >> 5;
    f32x4 acc[4];
#pragma unroll
    for (int j = 0; j < 4; ++j) acc[j] = (f32x4){0.f, 0.f, 0.f, 0.f};
    const float* xpb = xp + ((size_t)(b * 4096 + n0)) * 256 + dh * 128 + dg * 4;

    for (int t = 0; t < 4; ++t) {
#pragma unroll
        for (int i = 0; i < 8; ++i) {
            int e = tid + i * 256;
            int mW = e >> 6, nn = e & 63;
            int nl = t * 64 + nn;
            wt[nn * 36 + mW] =
                __expf(z_s[mW * 257 + nl] + u_s[mW] + v3_s[nl] - NORM_C) * inv_s[nl];
        }
        __syncthreads();
#pragma unroll 4
        for (int nn = 0; nn < 64; ++nn) {
            float4 xv = *(const float4*)(xpb + (size_t)(t * 64 + nn) * 256);
            float4 wv = *(const float4*)&wt[nn * 36 + mq * 4];
            acc[0].x += wv.x * xv.x; acc[0].y += wv.x * xv.y; acc[0].z += wv.x * xv.z; acc[0].w += wv.x * xv.w;
            acc[1].x += wv.y * xv.x; acc[1].y += wv.y * xv.y; acc[1].z += wv.y * xv.z; acc[1].w += wv.y * xv.w;
            acc[2].x += wv.z * xv.x; acc[2].y += wv.z * xv.y; acc[2].z += wv.z * xv.z; acc[2].w += wv.z * xv.w;
            acc[3].x += wv.w * xv.x; acc[3].y += wv.w * xv.y; acc[3].z += wv.w * xv.z; acc[3].w += wv.w * xv.w;
        }
        __syncthreads();
    }
#pragma unroll
    for (int j = 0; j < 4; ++j) {
        int m = mq * 4 + j;
        *(f32x4*)&part[((size_t)(b * 16 + chunk)) * 8192 + m * 256 + dh * 128 + dg * 4] = acc[j];
    }
}

// ---------------------------------------------------------------------------
// K5: reduce 16 chunk-partials -> v_tilde
// ---------------------------------------------------------------------------
__global__ __launch_bounds__(256) void vtilde_reduce(const float* __restrict__ part,
                                                     float* __restrict__ out_vt) {
    int o = blockIdx.x * 256 + threadIdx.x;
    int b = o >> 13, r = o & 8191;
    float s = 0.f;
#pragma unroll
    for (int c = 0; c < 16; ++c)
        s += part[((size_t)(b * 16 + c)) * 8192 + r];
    out_vt[o] = s;
}

// ---------------------------------------------------------------------------
extern "C" void kernel_launch(void* const* d_in, const int* in_sizes, int n_in,
                              void* d_out, int out_size, void* d_ws, size_t ws_size,
                              hipStream_t stream) {
    const float* x      = (const float*)d_in[0];
    const float* conv_w = (const float*)d_in[1];
    const float* conv_b = (const float*)d_in[2];
    const float* v_in   = (const float*)d_in[3];

    float* out_vt = (float*)d_out;                 // [16][32][256]
    float* out_xp = (float*)d_out + 131072;        // [16][4096][256]

    float* ws = (float*)d_ws;
    float*          inv_norm = ws;                                  // 65536 f
    unsigned short* Wb       = (unsigned short*)(ws + 65536);       // 196608 bf16
    unsigned short* wnb      = (unsigned short*)(ws + 163840);      // 8192 bf16
    float*          Zbuf     = ws + 167936;                         // 2097152 f
    float*          part     = ws + 2265088;                        // 2097152 f
    // u1p aliases the part region: written by conv_mega, fully consumed by
    // sink_step<32> BEFORE vtilde_part_k writes part. 16*32*32 float2 fits.
    float2*         u1p      = (float2*)part;
    float2*         u2p      = (float2*)(ws + 4362240);             // 8192 float2
    float2*         u3p      = (float2*)(ws + 4378624);             // 8192 float2

    w_prep<<<800, 64, 0, stream>>>(conv_w, v_in, Wb, wnb);
    conv_mega<<<dim3(32, 16), 256, 0, stream>>>(x, Wb, conv_b, wnb, out_xp,
                                                inv_norm, Zbuf, u1p);
    sink_step<32><<<dim3(16, 16), 256, 0, stream>>>(Zbuf, u1p, u2p);  // u1 -> v1 -> u2 partials
    sink_step<16><<<dim3(16, 16), 256, 0, stream>>>(Zbuf, u2p, u3p);  // u2 -> v2 -> u3 partials
    vtilde_part_k<<<dim3(32, 16), 256, 0, stream>>>(out_xp, inv_norm, Zbuf, u3p, part);
    vtilde_reduce<<<512, 256, 0, stream>>>(part, out_vt);
}

// Round 4
// 387.998 us; speedup vs baseline: 1.0694x; 1.0111x over previous
//
#include <hip/hip_runtime.h>
#include <math.h>

#define NORM_C (-8.3255483f)   /* -log(32+4096) */

typedef __attribute__((ext_vector_type(8))) short bf16x8;
typedef __attribute__((ext_vector_type(4))) float f32x4;

union U8 { uint4 q; unsigned u[4]; bf16x8 v; };

__device__ inline unsigned short f2bf_rne(float f) {
    unsigned u = __float_as_uint(f);
    unsigned r = u + 0x7fffu + ((u >> 16) & 1u);
    return (unsigned short)(r >> 16);
}
// pack two floats -> (bf16(hi)<<16)|bf16(lo)
__device__ inline unsigned pack_bf2(float lo, float hi) {
    unsigned a = __float_as_uint(lo) + 0x8000u;
    unsigned b = __float_as_uint(hi) + 0x8000u;
    return __builtin_amdgcn_perm(b, a, 0x07060302u);
}

// ---------------------------------------------------------------------------
// K0: fused prep. blocks 0..767: conv_w fp32->bf16. blocks 768..799: normalize
// clusters v[32][256] -> bf16.
// ---------------------------------------------------------------------------
__global__ __launch_bounds__(64) void w_prep(const float* __restrict__ W,
                                             const float* __restrict__ v_in,
                                             unsigned short* __restrict__ Wb,
                                             unsigned short* __restrict__ wnb) {
    const int bx = blockIdx.x, tid = threadIdx.x;
    if (bx < 768) {
        int i = (bx * 64 + tid) * 4;
        float4 w = *(const float4*)(W + i);
        unsigned lo = (unsigned)f2bf_rne(w.x) | ((unsigned)f2bf_rne(w.y) << 16);
        unsigned hi = (unsigned)f2bf_rne(w.z) | ((unsigned)f2bf_rne(w.w) << 16);
        *(uint2*)(Wb + i) = make_uint2(lo, hi);
    } else {
        int row = bx - 768;
        float4 v = *(const float4*)(v_in + row * 256 + tid * 4);
        float s = v.x * v.x + v.y * v.y + v.z * v.z + v.w * v.w;
#pragma unroll
        for (int off = 32; off > 0; off >>= 1) s += __shfl_xor(s, off);
        float inv = 1.0f / fmaxf(sqrtf(s), 1e-12f);
        unsigned lo = (unsigned)f2bf_rne(v.x * inv) | ((unsigned)f2bf_rne(v.y * inv) << 16);
        unsigned hi = (unsigned)f2bf_rne(v.z * inv) | ((unsigned)f2bf_rne(v.w * inv) << 16);
        *(uint2*)(wnb + row * 256 + tid * 4) = make_uint2(lo, hi);
    }
}

// ---------------------------------------------------------------------------
// K1: mega kernel (round-0 structure). ONLY change vs round 0: the Bs x-tile
// is ch-major [16][132] (pad 132 -> MFMA b-fragment reads are 2-way = free),
// staged with 4x float4 global loads + 2x ds_write_b128 per thread per k-step
// (contiguous, conflict-free writes) instead of 8x float2 + 8x b32 (4-way
// write conflicts, 2x the load instructions).
// Block: 128 n x 256 d (full), 4 waves (wn x wd).
// ---------------------------------------------------------------------------
__global__ __launch_bounds__(256) void conv_mega(const float* __restrict__ x,
                                                 const unsigned short* __restrict__ Wb,
                                                 const float* __restrict__ bias,
                                                 const unsigned short* __restrict__ wnb,
                                                 float* __restrict__ xp,
                                                 float* __restrict__ inv_norm,
                                                 float* __restrict__ Z,
                                                 float2* __restrict__ u1p) {
    __shared__ unsigned As[256 * 20];    // W tile 256d x 32k (pad 20)
    __shared__ unsigned Bs[16 * 132];    // x tile ch-major: 16 k-pairs x 128n (pad 132)
    __shared__ float ssq_s[128];
    __shared__ float invs_s[128];
    __shared__ unsigned xfs[128 * 33];   // xf quarter: 128n x 64d (bf16 pairs)
    __shared__ float2 upart_s[4][32];

    const int tid = threadIdx.x;
    const int lane = tid & 63;
    const int wid = tid >> 6;
    const int wn = wid & 1, wd = wid >> 1;
    const int b = blockIdx.y;
    const int n0 = blockIdx.x * 128;
    const int l15 = lane & 15, l4 = lane >> 4;
    const float* xb = x + (size_t)b * 768 * 4096;

    f32x4 acc[8][4];
#pragma unroll
    for (int i = 0; i < 8; ++i)
#pragma unroll
        for (int j = 0; j < 4; ++j) acc[i][j] = (f32x4){0.f, 0.f, 0.f, 0.f};

    // ---------------- phase 1: conv ----------------
    for (int k0 = 0; k0 < 768; k0 += 32) {
        __syncthreads();
#pragma unroll
        for (int i = 0; i < 4; ++i) {
            int f = tid + i * 256;
            int dd = f >> 2, c8 = f & 3;
            uint4 w = *(const uint4*)(Wb + (size_t)dd * 768 + k0 + c8 * 8);
            *(uint4*)&As[dd * 20 + c8 * 4] = w;
        }
#pragma unroll
        for (int i = 0; i < 2; ++i) {
            int f = tid + i * 256;          // 0..511
            int n4 = f & 31, ch = f >> 5;   // 4-n group, k-pair channel
            const float* p = xb + (size_t)(k0 + 2 * ch) * 4096 + n0 + 4 * n4;
            float4 g0 = *(const float4*)p;
            float4 g1 = *(const float4*)(p + 4096);
            uint4 w;
            w.x = pack_bf2(g0.x, g1.x);
            w.y = pack_bf2(g0.y, g1.y);
            w.z = pack_bf2(g0.z, g1.z);
            w.w = pack_bf2(g0.w, g1.w);
            *(uint4*)&Bs[ch * 132 + 4 * n4] = w;
        }
        __syncthreads();

        U8 af[8];
#pragma unroll
        for (int dt = 0; dt < 8; ++dt) {
            int row = wd * 128 + dt * 16 + l15;
            af[dt].q = *(uint4*)&As[row * 20 + l4 * 4];
        }
#pragma unroll
        for (int nt = 0; nt < 4; ++nt) {
            int col = wn * 64 + nt * 16 + l15;
            U8 bf;
            bf.u[0] = Bs[(l4 * 4 + 0) * 132 + col];
            bf.u[1] = Bs[(l4 * 4 + 1) * 132 + col];
            bf.u[2] = Bs[(l4 * 4 + 2) * 132 + col];
            bf.u[3] = Bs[(l4 * 4 + 3) * 132 + col];
#pragma unroll
            for (int dt = 0; dt < 8; ++dt)
                acc[dt][nt] = __builtin_amdgcn_mfma_f32_16x16x32_bf16(
                    af[dt].v, bf.v, acc[dt][nt], 0, 0, 0);
        }
    }

    // epilogue: bias into acc, store xp, row sum-of-squares -> inv_norm
    float ssq[4] = {0.f, 0.f, 0.f, 0.f};
#pragma unroll
    for (int dt = 0; dt < 8; ++dt) {
        int d = wd * 128 + dt * 16 + l4 * 4;
        float4 bi = *(const float4*)(bias + d);
#pragma unroll
        for (int nt = 0; nt < 4; ++nt) {
            int n = n0 + wn * 64 + nt * 16 + l15;
            f32x4 o = acc[dt][nt];
            o.x += bi.x; o.y += bi.y; o.z += bi.z; o.w += bi.w;
            acc[dt][nt] = o;
            *(f32x4*)(xp + ((size_t)(b * 4096 + n)) * 256 + d) = o;
            ssq[nt] += o.x * o.x + o.y * o.y + o.z * o.z + o.w * o.w;
        }
    }
#pragma unroll
    for (int nt = 0; nt < 4; ++nt) {
        ssq[nt] += __shfl_xor(ssq[nt], 16);
        ssq[nt] += __shfl_xor(ssq[nt], 32);
    }
    if (wd == 0 && l4 == 0) {
#pragma unroll
        for (int nt = 0; nt < 4; ++nt) ssq_s[wn * 64 + nt * 16 + l15] = ssq[nt];
    }
    __syncthreads();
    if (wd == 1 && l4 == 0) {
#pragma unroll
        for (int nt = 0; nt < 4; ++nt) {
            int nl = wn * 64 + nt * 16 + l15;
            float inv = 1.0f / fmaxf(sqrtf(ssq[nt] + ssq_s[nl]), 1e-12f);
            invs_s[nl] = inv;
            inv_norm[b * 4096 + n0 + nl] = inv;
        }
    }

    // ---------------- phase 2: scores + u1 partials ----------------
    f32x4 accz[2][2];
#pragma unroll
    for (int i = 0; i < 2; ++i)
#pragma unroll
        for (int j = 0; j < 2; ++j) accz[i][j] = (f32x4){0.f, 0.f, 0.f, 0.f};

    for (int q = 0; q < 4; ++q) {
        __syncthreads();
        if (wd == (q >> 1)) {
#pragma unroll
            for (int dt4 = 0; dt4 < 4; ++dt4) {
                int dt = (q & 1) * 4 + dt4;
#pragma unroll
                for (int nt = 0; nt < 4; ++nt) {
                    int n = wn * 64 + nt * 16 + l15;
                    float inv = invs_s[n];
                    f32x4 a = acc[dt][nt];
                    int base = n * 33 + dt4 * 8 + l4 * 2;
                    xfs[base]     = pack_bf2(a.x * inv, a.y * inv);
                    xfs[base + 1] = pack_bf2(a.z * inv, a.w * inv);
                }
            }
        }
        __syncthreads();
#pragma unroll
        for (int s = 0; s < 2; ++s) {
            U8 wf[2];
#pragma unroll
            for (int mt = 0; mt < 2; ++mt)
                wf[mt].q = *(const uint4*)(wnb + (mt * 16 + l15) * 256 +
                                           q * 64 + s * 32 + l4 * 8);
#pragma unroll
            for (int sti = 0; sti < 2; ++sti) {
                int st = wid + sti * 4;
                int arow = (st * 16 + l15) * 33 + s * 16 + l4 * 4;
                U8 af;
                af.u[0] = xfs[arow]; af.u[1] = xfs[arow + 1];
                af.u[2] = xfs[arow + 2]; af.u[3] = xfs[arow + 3];
#pragma unroll
                for (int mt = 0; mt < 2; ++mt)
                    accz[sti][mt] = __builtin_amdgcn_mfma_f32_16x16x32_bf16(
                        af.v, wf[mt].v, accz[sti][mt], 0, 0, 0);
            }
        }
    }
    // scale by 1/EPS, write Z, emit u1 partials
#pragma unroll
    for (int sti = 0; sti < 2; ++sti)
#pragma unroll
        for (int mt = 0; mt < 2; ++mt) {
            accz[sti][mt].x *= 20.f; accz[sti][mt].y *= 20.f;
            accz[sti][mt].z *= 20.f; accz[sti][mt].w *= 20.f;
            int m = mt * 16 + l15;
            int st = wid + sti * 4;
            *(f32x4*)&Z[((size_t)(b * 32 + m)) * 4096 + n0 + st * 16 + l4 * 4] =
                accz[sti][mt];
        }
#pragma unroll
    for (int mt = 0; mt < 2; ++mt) {
        float v0[8] = {accz[0][mt].x, accz[0][mt].y, accz[0][mt].z, accz[0][mt].w,
                       accz[1][mt].x, accz[1][mt].y, accz[1][mt].z, accz[1][mt].w};
        float mx = v0[0];
#pragma unroll
        for (int i = 1; i < 8; ++i) mx = fmaxf(mx, v0[i]);
        float s = 0.f;
#pragma unroll
        for (int i = 0; i < 8; ++i) s += __expf(v0[i] - mx);
#pragma unroll
        for (int off = 16; off < 64; off <<= 1) {
            float omx = __shfl_xor(mx, off);
            float os = __shfl_xor(s, off);
            float nm = fmaxf(mx, omx);
            s = s * __expf(mx - nm) + os * __expf(omx - nm);
            mx = nm;
        }
        if (lane < 16) upart_s[wid][mt * 16 + lane] = make_float2(mx, s);
    }
    __syncthreads();
    if (wid == 0 && lane < 32) {
        float2 p = upart_s[0][lane];
        float mx = p.x, s = p.y;
#pragma unroll
        for (int w = 1; w < 4; ++w) {
            float2 qq = upart_s[w][lane];
            float nm = fmaxf(mx, qq.x);
            s = s * __expf(mx - nm) + qq.y * __expf(qq.x - nm);
            mx = nm;
        }
        u1p[((size_t)b * 32 + blockIdx.x) * 32 + lane] = make_float2(mx, s);
    }
}

// ---------------------------------------------------------------------------
// K2: sinkhorn v-update (round-0 version). FIRST=1: derive u from u1
// partials; else from u_g.
// ---------------------------------------------------------------------------
template <int FIRST>
__global__ __launch_bounds__(512) void sink_v(const float* __restrict__ Z,
                                              const float2* __restrict__ u1p,
                                              const float* __restrict__ u_g,
                                              float* __restrict__ v_g) {
    __shared__ float u_s[32];
    const int tid = threadIdx.x;
    const int b = blockIdx.y;
    const int n = blockIdx.x * 512 + tid;
    if (tid < 32) {
        if (FIRST) {
            float2 p = u1p[((size_t)b * 32) * 32 + tid];
            float mx = p.x, s = p.y;
#pragma unroll 4
            for (int t = 1; t < 32; ++t) {
                float2 q = u1p[((size_t)b * 32 + t) * 32 + tid];
                float nm = fmaxf(mx, q.x);
                s = s * __expf(mx - nm) + q.y * __expf(q.x - nm);
                mx = nm;
            }
            u_s[tid] = NORM_C - (mx + __logf(s));
        } else {
            u_s[tid] = u_g[b * 32 + tid];
        }
    }
    __syncthreads();
    float z[32];
#pragma unroll
    for (int m = 0; m < 32; ++m) z[m] = Z[((size_t)(b * 32 + m)) * 4096 + n] + u_s[m];
    float mx = z[0];
#pragma unroll
    for (int m = 1; m < 32; ++m) mx = fmaxf(mx, z[m]);
    float s = 0.f;
#pragma unroll
    for (int m = 0; m < 32; ++m) s += __expf(z[m] - mx);
    v_g[b * 4096 + n] = NORM_C - (mx + __logf(s));
}

// ---------------------------------------------------------------------------
// K3: sinkhorn u-update (round-0 version): one block per (b,m); LSE over
// 4096 n of Z+v.
// ---------------------------------------------------------------------------
__global__ __launch_bounds__(256) void sink_u(const float* __restrict__ Z,
                                              const float* __restrict__ v_g,
                                              float* __restrict__ u_g) {
    __shared__ float wmx[4], wsum[4];
    const int tid = threadIdx.x;
    const int lane = tid & 63, wid = tid >> 6;
    const int b = blockIdx.x >> 5, m = blockIdx.x & 31;
    const float* zr = Z + ((size_t)(b * 32 + m)) * 4096;
    const float* vr = v_g + b * 4096;

    float z[16];
#pragma unroll
    for (int j = 0; j < 16; ++j) {
        int n = tid + j * 256;
        z[j] = zr[n] + vr[n];
    }
    float mx = z[0];
#pragma unroll
    for (int j = 1; j < 16; ++j) mx = fmaxf(mx, z[j]);
    float s = 0.f;
#pragma unroll
    for (int j = 0; j < 16; ++j) s += __expf(z[j] - mx);
#pragma unroll
    for (int off = 1; off < 64; off <<= 1) {
        float omx = __shfl_xor(mx, off);
        float os = __shfl_xor(s, off);
        float nm = fmaxf(mx, omx);
        s = s * __expf(mx - nm) + os * __expf(omx - nm);
        mx = nm;
    }
    if (lane == 0) { wmx[wid] = mx; wsum[wid] = s; }
    __syncthreads();
    if (tid == 0) {
        float gm = wmx[0], gs = wsum[0];
#pragma unroll
        for (int w = 1; w < 4; ++w) {
            float nm = fmaxf(gm, wmx[w]);
            gs = gs * __expf(gm - nm) + wsum[w] * __expf(wmx[w] - nm);
            gm = nm;
        }
        u_g[b * 32 + m] = NORM_C - (gm + __logf(gs));
    }
}

// ---------------------------------------------------------------------------
// K4: v_tilde partials (round-0 version). v3 computed inline from u3 (= u_g).
// Block: (chunk of 256 n x d-half 128, b). Thread: 4 d x 4 m.
// ---------------------------------------------------------------------------
__global__ __launch_bounds__(256) void vtilde_part_k(const float* __restrict__ xp,
                                                     const float* __restrict__ inv_norm,
                                                     const float* __restrict__ Z,
                                                     const float* __restrict__ u_g,
                                                     float* __restrict__ part) {
    __shared__ float u_s[32];
    __shared__ float v3_s[256];
    __shared__ float inv_s[256];
    __shared__ float wt[64 * 36];
    const int tid = threadIdx.x;
    const int cx = blockIdx.x;
    const int chunk = cx >> 1, dh = cx & 1;
    const int b = blockIdx.y;
    const int n0 = chunk * 256;
    if (tid < 32) u_s[tid] = u_g[b * 32 + tid];
    __syncthreads();
    {
        int n = n0 + tid;
        float z[32];
#pragma unroll
        for (int m = 0; m < 32; ++m)
            z[m] = Z[((size_t)(b * 32 + m)) * 4096 + n] + u_s[m];
        float mx = z[0];
#pragma unroll
        for (int m = 1; m < 32; ++m) mx = fmaxf(mx, z[m]);
        float s = 0.f;
#pragma unroll
        for (int m = 0; m < 32; ++m) s += __expf(z[m] - mx);
        v3_s[tid] = NORM_C - (mx + __logf(s));
        inv_s[tid] = inv_norm[b * 4096 + n];
    }
    __syncthreads();

    const int dg = tid & 31, mq = tid >> 5;
    f32x4 acc[4];
#pragma unroll
    for (int j = 0; j < 4; ++j) acc[j] = (f32x4){0.f, 0.f, 0.f, 0.f};
    const float* xpb = xp + ((size_t)(b * 4096 + n0)) * 256 + dh * 128 + dg * 4;

    for (int t = 0; t < 4; ++t) {
#pragma unroll
        for (int i = 0; i < 8; ++i) {
            int e = tid + i * 256;
            int mW = e >> 6, nn = e & 63;
            int nl = t * 64 + nn;
            wt[nn * 36 + mW] =
                __expf(Z[((size_t)(b * 32 + mW)) * 4096 + n0 + nl] + u_s[mW] +
                       v3_s[nl] - NORM_C) * inv_s[nl];
        }
        __syncthreads();
#pragma unroll 4
        for (int nn = 0; nn < 64; ++nn) {
            float4 xv = *(const float4*)(xpb + (size_t)(t * 64 + nn) * 256);
            float4 wv = *(const float4*)&wt[nn * 36 + mq * 4];
            acc[0].x += wv.x * xv.x; acc[0].y += wv.x * xv.y; acc[0].z += wv.x * xv.z; acc[0].w += wv.x * xv.w;
            acc[1].x += wv.y * xv.x; acc[1].y += wv.y * xv.y; acc[1].z += wv.y * xv.z; acc[1].w += wv.y * xv.w;
            acc[2].x += wv.z * xv.x; acc[2].y += wv.z * xv.y; acc[2].z += wv.z * xv.z; acc[2].w += wv.z * xv.w;
            acc[3].x += wv.w * xv.x; acc[3].y += wv.w * xv.y; acc[3].z += wv.w * xv.z; acc[3].w += wv.w * xv.w;
        }
        __syncthreads();
    }
#pragma unroll
    for (int j = 0; j < 4; ++j) {
        int m = mq * 4 + j;
        *(f32x4*)&part[((size_t)(b * 16 + chunk)) * 8192 + m * 256 + dh * 128 + dg * 4] = acc[j];
    }
}

// ---------------------------------------------------------------------------
// K5: reduce 16 chunk-partials -> v_tilde
// ---------------------------------------------------------------------------
__global__ __launch_bounds__(256) void vtilde_reduce(const float* __restrict__ part,
                                                     float* __restrict__ out_vt) {
    int o = blockIdx.x * 256 + threadIdx.x;
    int b = o >> 13, r = o & 8191;
    float s = 0.f;
#pragma unroll
    for (int c = 0; c < 16; ++c)
        s += part[((size_t)(b * 16 + c)) * 8192 + r];
    out_vt[o] = s;
}

// ---------------------------------------------------------------------------
extern "C" void kernel_launch(void* const* d_in, const int* in_sizes, int n_in,
                              void* d_out, int out_size, void* d_ws, size_t ws_size,
                              hipStream_t stream) {
    const float* x      = (const float*)d_in[0];
    const float* conv_w = (const float*)d_in[1];
    const float* conv_b = (const float*)d_in[2];
    const float* v_in   = (const float*)d_in[3];

    float* out_vt = (float*)d_out;                 // [16][32][256]
    float* out_xp = (float*)d_out + 131072;        // [16][4096][256]

    float* ws = (float*)d_ws;
    float*          inv_norm = ws;                                  // 65536
    unsigned short* Wb       = (unsigned short*)(ws + 65536);       // 196608 bf16
    unsigned short* wnb      = (unsigned short*)(ws + 163840);      // 8192 bf16
    float*          Zbuf     = ws + 167936;                         // 2097152
    float2*         u1p      = (float2*)(ws + 2265088);             // 16384 float2
    float*          u_g      = ws + 2297856;                        // 512
    float*          v_g      = ws + 2298368;                        // 65536
    float*          part     = ws + 2363904;                        // 2097152

    w_prep<<<800, 64, 0, stream>>>(conv_w, v_in, Wb, wnb);
    conv_mega<<<dim3(32, 16), 256, 0, stream>>>(x, Wb, conv_b, wnb, out_xp,
                                                inv_norm, Zbuf, u1p);
    sink_v<1><<<dim3(8, 16), 512, 0, stream>>>(Zbuf, u1p, u_g, v_g);   // v1 (u1 from partials)
    sink_u<<<512, 256, 0, stream>>>(Zbuf, v_g, u_g);                   // u2
    sink_v<0><<<dim3(8, 16), 512, 0, stream>>>(Zbuf, u1p, u_g, v_g);   // v2
    sink_u<<<512, 256, 0, stream>>>(Zbuf, v_g, u_g);                   // u3
    vtilde_part_k<<<dim3(32, 16), 256, 0, stream>>>(out_xp, inv_norm, Zbuf, u_g, part);
    vtilde_reduce<<<512, 256, 0, stream>>>(part, out_vt);
}